// Round 1
// baseline (2146.022 us; speedup 1.0000x reference)
//
#include <hip/hip_runtime.h>
#include <math.h>

#define B_  128
#define P_  2048
#define NB_ 2000
#define NF_ 250
#define NC_ 16
#define R_  128
#define LS_ 1750   // NB-NF (len_sim)
#define NT_ 1751   // NB-NF+1

// ---------------- filt_time[t] = sum_k stim_time[t+k]*stf[k], f64 ----------------
__global__ void k_ft(const float* __restrict__ st, const float* __restrict__ stf,
                     double* __restrict__ ft) {
    int t = blockIdx.x * 256 + threadIdx.x;
    if (t >= NT_) return;
    double s = 0.0;
    for (int k = 0; k < NF_; ++k) s += (double)st[t + k] * (double)stf[k];
    ft[t] = s;
}

// ---------------- sdot[b] = stim_spat[b,:] . spatial_filter, f64 ----------------
__global__ __launch_bounds__(256) void k_sdot(const float* __restrict__ sp,
                                              const float* __restrict__ sf,
                                              double* __restrict__ sdot) {
    __shared__ double red[256];
    int b = blockIdx.x;
    double s = 0.0;
    for (int p = threadIdx.x; p < P_; p += 256)
        s += (double)sp[(size_t)b * P_ + p] * (double)sf[p];
    red[threadIdx.x] = s;
    __syncthreads();
    for (int off = 128; off > 0; off >>= 1) {
        if (threadIdx.x < off) red[threadIdx.x] += red[threadIdx.x + off];
        __syncthreads();
    }
    if (threadIdx.x == 0) sdot[b] = red[0];
}

// ---------------- gensig[b,t] = sdot[b]*ft[t] + bias + coup[b,t], f64 ----------------
// One wave (64 threads) per (b, 256-wide t-tile); each lane computes 4 consecutive t.
__global__ __launch_bounds__(64) void k_coup(const float* __restrict__ cc,
                                             const float* __restrict__ cf,
                                             const double* __restrict__ sdot,
                                             const double* __restrict__ ft,
                                             const float* __restrict__ bias,
                                             double* __restrict__ gensig) {
    __shared__ __align__(16) float  ccs[NC_ * 512];   // 32 KB
    __shared__ __align__(16) double cfs[NC_ * 256];   // 32 KB
    int b = blockIdx.y, t0 = blockIdx.x * 256, lane = threadIdx.x;

    // stage coupling cells window [t0, t0+512)
    for (int idx = lane; idx < NC_ * 128; idx += 64) {
        int c = idx >> 7, j4 = (idx & 127) * 4, src = t0 + j4;
        const float* p = cc + ((size_t)b * NC_ + c) * NB_ + src;
        float4 v;
        if (src + 3 < NB_) v = *(const float4*)p;
        else {
            v.x = (src     < NB_) ? p[0] : 0.f;
            v.y = (src + 1 < NB_) ? p[1] : 0.f;
            v.z = (src + 2 < NB_) ? p[2] : 0.f;
            v.w = (src + 3 < NB_) ? p[3] : 0.f;
        }
        *(float4*)&ccs[c * 512 + j4] = v;
    }
    // stage coupling filter as f64, zero-padded to 256
    for (int idx = lane; idx < NC_ * 256; idx += 64) {
        int c = idx >> 8, k = idx & 255;
        cfs[idx] = (k < NF_) ? (double)cf[c * NF_ + k] : 0.0;
    }
    __syncthreads();

    double a0 = 0, a1 = 0, a2 = 0, a3 = 0;
    int base = lane * 4;
    for (int c = 0; c < NC_; ++c) {
        const float*  row  = &ccs[c * 512];
        const double* crow = &cfs[c * 256];
        float4 cur = *(const float4*)&row[base];
        for (int k4 = 0; k4 < 252; k4 += 4) {
            float4 nxt = *(const float4*)&row[base + k4 + 4];
            double e0 = cur.x, e1 = cur.y, e2 = cur.z, e3 = cur.w;
            double e4 = nxt.x, e5 = nxt.y, e6 = nxt.z;
            double c0 = crow[k4], c1 = crow[k4 + 1], c2 = crow[k4 + 2], c3 = crow[k4 + 3];
            a0 += e0 * c0 + e1 * c1 + e2 * c2 + e3 * c3;
            a1 += e1 * c0 + e2 * c1 + e3 * c2 + e4 * c3;
            a2 += e2 * c0 + e3 * c1 + e4 * c2 + e5 * c3;
            a3 += e3 * c0 + e4 * c1 + e5 * c2 + e6 * c3;
            cur = nxt;
        }
    }
    double gb = (double)bias[0];
    double sd = sdot[b];
    double accs[4] = {a0, a1, a2, a3};
    int tb = t0 + base;
    for (int i = 0; i < 4; ++i) {
        int t = tb + i;
        if (t < LS_) gensig[(size_t)b * LS_ + t] = sd * ft[t] + gb + accs[i];
    }
}

// ---------------- out[:, :, 0:250] = initial spike section (broadcast over r) ----------------
__global__ void k_copy0(const float* __restrict__ iss, float* __restrict__ out) {
    int i = blockIdx.x * 256 + threadIdx.x;
    if (i >= B_ * R_ * NF_) return;
    int k = i % NF_;
    int br = i / NF_;
    int b = br >> 7;
    out[(size_t)br * NB_ + k] = iss[b * NF_ + k];
}

// ---------------- the sequential scan: 1 chain per thread ----------------
// fb via byte-LUT: T[pos][byte] = sum over set bits of ff[8*pos+i]  (f64, 64KB LDS)
__global__ __launch_bounds__(64) void k_scan(const double* __restrict__ gensig,
                                             const float* __restrict__ u,
                                             const float* __restrict__ iss,
                                             const float* __restrict__ ff,
                                             float* __restrict__ out) {
    __shared__ double T[32 * 256];   // exactly 64 KB
    int lane = threadIdx.x;
    int b = blockIdx.x >> 1, half = blockIdx.x & 1;
    int r = half * 64 + lane;

    // build LUT: 2 lanes per pos, 128 entries each
    {
        int pos = lane >> 1;
        double f[8];
#pragma unroll
        for (int i = 0; i < 8; ++i) {
            int k = pos * 8 + i;
            f[i] = (k < NF_) ? (double)ff[k] : 0.0;
        }
        int mbase = (lane & 1) * 128;
        for (int m0 = 0; m0 < 128; ++m0) {
            int m = mbase + m0;
            double s = 0.0;
#pragma unroll
            for (int i = 0; i < 8; ++i)
                if ((m >> i) & 1) s += f[i];
            T[pos * 256 + m] = s;
        }
    }

    // init window: bit k = initial_spike_section[b,k]  (window[k] = spike at abs time t+k)
    unsigned long long w0 = 0, w1 = 0, w2 = 0, w3 = 0;
    for (int k = 0; k < NF_; ++k) {
        unsigned long long bit = (iss[b * NF_ + k] > 0.5f) ? 1ull : 0ull;
        if      (k <  64) w0 |= bit << k;
        else if (k < 128) w1 |= bit << (k - 64);
        else if (k < 192) w2 |= bit << (k - 128);
        else              w3 |= bit << (k - 192);
    }
    __syncthreads();

    const double* gs = gensig + (size_t)b * LS_;
    const float*  up = u + (size_t)b * R_ + r;
    float*        op = out + ((size_t)(b * R_ + r)) * NB_ + NF_;

    float  un = up[0];
    double gn = gs[0];

    for (int t = 0; t < LS_; ++t) {
        float  uc = un;
        double gc = gn;
        if (t + 1 < LS_) {
            un = up[(size_t)(t + 1) * (B_ * R_)];
            gn = gs[t + 1];
        }
        // logit(u) in f64: spike = (u < sigmoid(g)) <=> (g > logit(u))
        double lu = log((double)uc) - log1p(-(double)uc);

        double f0 = 0, f1 = 0, f2 = 0, f3 = 0;
#define LK(W, J, POS, ACC) { unsigned byt = (unsigned)((W) >> ((J) * 8)) & 255u; \
                             ACC += T[(POS) * 256 + byt]; }
        LK(w0, 0,  0, f0) LK(w0, 1,  1, f1) LK(w0, 2,  2, f2) LK(w0, 3,  3, f3)
        LK(w0, 4,  4, f0) LK(w0, 5,  5, f1) LK(w0, 6,  6, f2) LK(w0, 7,  7, f3)
        LK(w1, 0,  8, f0) LK(w1, 1,  9, f1) LK(w1, 2, 10, f2) LK(w1, 3, 11, f3)
        LK(w1, 4, 12, f0) LK(w1, 5, 13, f1) LK(w1, 6, 14, f2) LK(w1, 7, 15, f3)
        LK(w2, 0, 16, f0) LK(w2, 1, 17, f1) LK(w2, 2, 18, f2) LK(w2, 3, 19, f3)
        LK(w2, 4, 20, f0) LK(w2, 5, 21, f1) LK(w2, 6, 22, f2) LK(w2, 7, 23, f3)
        LK(w3, 0, 24, f0) LK(w3, 1, 25, f1) LK(w3, 2, 26, f2) LK(w3, 3, 27, f3)
        LK(w3, 4, 28, f0) LK(w3, 5, 29, f1) LK(w3, 6, 30, f2) LK(w3, 7, 31, f3)
#undef LK
        double g = gc + ((f0 + f1) + (f2 + f3));
        bool sp = (g > lu);

        // window[k] <- window[k+1]; window[249] <- spike  (bit 249 = w3 bit 57)
        w0 = (w0 >> 1) | (w1 << 63);
        w1 = (w1 >> 1) | (w2 << 63);
        w2 = (w2 >> 1) | (w3 << 63);
        w3 = (w3 >> 1) | ((unsigned long long)(sp ? 1 : 0) << 57);

        op[t] = sp ? 1.0f : 0.0f;
    }
}

extern "C" void kernel_launch(void* const* d_in, const int* in_sizes, int n_in,
                              void* d_out, int out_size, void* d_ws, size_t ws_size,
                              hipStream_t stream) {
    const float* stim_spat = (const float*)d_in[0];   // (128,2048)
    const float* stim_time = (const float*)d_in[1];   // (2000,)
    const float* iss       = (const float*)d_in[2];   // (128,250)
    const float* cc        = (const float*)d_in[3];   // (128,16,2000)
    const float* sf        = (const float*)d_in[4];   // (2048,)
    const float* bias      = (const float*)d_in[5];   // (1,)
    const float* stf       = (const float*)d_in[6];   // (250,)
    const float* ff        = (const float*)d_in[7];   // (250,)
    const float* cf        = (const float*)d_in[8];   // (16,250)
    const float* u         = (const float*)d_in[9];   // (1750,128,128)
    (void)in_sizes; (void)n_in; (void)out_size; (void)ws_size;

    float* out = (float*)d_out;                       // (128,128,2000)

    double* ws     = (double*)d_ws;
    double* gensig = ws;                              // 128*1750 f64
    double* ft     = gensig + (size_t)B_ * LS_;       // 1751 f64
    double* sdot   = ft + NT_;                        // 128 f64

    k_ft   <<<(NT_ + 255) / 256, 256, 0, stream>>>(stim_time, stf, ft);
    k_sdot <<<B_, 256, 0, stream>>>(stim_spat, sf, sdot);
    k_coup <<<dim3(7, B_), 64, 0, stream>>>(cc, cf, sdot, ft, bias, gensig);
    k_copy0<<<(B_ * R_ * NF_ + 255) / 256, 256, 0, stream>>>(iss, out);
    k_scan <<<B_ * 2, 64, 0, stream>>>(gensig, u, iss, ff, out);
}

// Round 3
// 971.679 us; speedup vs baseline: 2.2086x; 2.2086x over previous
//
#include <hip/hip_runtime.h>
#include <math.h>

#define B_  128
#define P_  2048
#define NB_ 2000
#define NF_ 250
#define NC_ 16
#define R_  128
#define LS_ 1750   // NB-NF (len_sim)
#define NT_ 1751   // NB-NF+1
#define BR_ (B_ * R_)

// ---- DPP quad-perm on f64 (2x mov_dpp b32). CTRL: perm[i] in 2-bit fields ----
template <int CTRL>
__device__ __forceinline__ double dpp64(double v) {
    long long x = __double_as_longlong(v);
    int lo = (int)x, hi = (int)(x >> 32);
    lo = __builtin_amdgcn_mov_dpp(lo, CTRL, 0xF, 0xF, true);
    hi = __builtin_amdgcn_mov_dpp(hi, CTRL, 0xF, 0xF, true);
    return __longlong_as_double(((long long)(unsigned)lo) | ((long long)hi << 32));
}
// xor1 = quad_perm[1,0,3,2] = 0xB1 ; xor2 = quad_perm[2,3,0,1] = 0x4E
// bcast s = quad_perm[s,s,s,s] = s*0x55

__device__ __forceinline__ double lu_of(float uf) {
    double u = (double)uf;
    return log(u / (1.0 - u));   // == logit(u); |err| ~1e-16, margin ~3e-8
}

// ---------------- filt_time[t] = sum_k stim_time[t+k]*stf[k], f64 ----------------
__global__ void k_ft(const float* __restrict__ st, const float* __restrict__ stf,
                     double* __restrict__ ft) {
    int t = blockIdx.x * 256 + threadIdx.x;
    if (t >= NT_) return;
    double s = 0.0;
    for (int k = 0; k < NF_; ++k) s += (double)st[t + k] * (double)stf[k];
    ft[t] = s;
}

// ---------------- sdot[b] = stim_spat[b,:] . spatial_filter, f64 ----------------
__global__ __launch_bounds__(256) void k_sdot(const float* __restrict__ sp,
                                              const float* __restrict__ sf,
                                              double* __restrict__ sdot) {
    __shared__ double red[256];
    int b = blockIdx.x;
    double s = 0.0;
    for (int p = threadIdx.x; p < P_; p += 256)
        s += (double)sp[(size_t)b * P_ + p] * (double)sf[p];
    red[threadIdx.x] = s;
    __syncthreads();
    for (int off = 128; off > 0; off >>= 1) {
        if (threadIdx.x < off) red[threadIdx.x] += red[threadIdx.x + off];
        __syncthreads();
    }
    if (threadIdx.x == 0) sdot[b] = red[0];
}

// ---------------- gensig[b,t] = sdot[b]*ft[t] + bias + coup[b,t], f64 ----------------
__global__ __launch_bounds__(64) void k_coup(const float* __restrict__ cc,
                                             const float* __restrict__ cf,
                                             const double* __restrict__ sdot,
                                             const double* __restrict__ ft,
                                             const float* __restrict__ bias,
                                             double* __restrict__ gensig) {
    __shared__ __align__(16) float  ccs[NC_ * 512];   // 32 KB
    __shared__ __align__(16) double cfs[NC_ * 256];   // 32 KB
    int b = blockIdx.y, t0 = blockIdx.x * 256, lane = threadIdx.x;

    for (int idx = lane; idx < NC_ * 128; idx += 64) {
        int c = idx >> 7, j4 = (idx & 127) * 4, src = t0 + j4;
        const float* p = cc + ((size_t)b * NC_ + c) * NB_ + src;
        float4 v;
        if (src + 3 < NB_) v = *(const float4*)p;
        else {
            v.x = (src     < NB_) ? p[0] : 0.f;
            v.y = (src + 1 < NB_) ? p[1] : 0.f;
            v.z = (src + 2 < NB_) ? p[2] : 0.f;
            v.w = (src + 3 < NB_) ? p[3] : 0.f;
        }
        *(float4*)&ccs[c * 512 + j4] = v;
    }
    for (int idx = lane; idx < NC_ * 256; idx += 64) {
        int c = idx >> 8, k = idx & 255;
        cfs[idx] = (k < NF_) ? (double)cf[c * NF_ + k] : 0.0;
    }
    __syncthreads();

    double a0 = 0, a1 = 0, a2 = 0, a3 = 0;
    int base = lane * 4;
    for (int c = 0; c < NC_; ++c) {
        const float*  row  = &ccs[c * 512];
        const double* crow = &cfs[c * 256];
        float4 cur = *(const float4*)&row[base];
        for (int k4 = 0; k4 < 252; k4 += 4) {
            float4 nxt = *(const float4*)&row[base + k4 + 4];
            double e0 = cur.x, e1 = cur.y, e2 = cur.z, e3 = cur.w;
            double e4 = nxt.x, e5 = nxt.y, e6 = nxt.z;
            double c0 = crow[k4], c1 = crow[k4 + 1], c2 = crow[k4 + 2], c3 = crow[k4 + 3];
            a0 += e0 * c0 + e1 * c1 + e2 * c2 + e3 * c3;
            a1 += e1 * c0 + e2 * c1 + e3 * c2 + e4 * c3;
            a2 += e2 * c0 + e3 * c1 + e4 * c2 + e5 * c3;
            a3 += e3 * c0 + e4 * c1 + e5 * c2 + e6 * c3;
            cur = nxt;
        }
    }
    double gb = (double)bias[0];
    double sd = sdot[b];
    double accs[4] = {a0, a1, a2, a3};
    int tb = t0 + base;
    for (int i = 0; i < 4; ++i) {
        int t = tb + i;
        if (t < LS_) gensig[(size_t)b * LS_ + t] = sd * ft[t] + gb + accs[i];
    }
}

// ---------------- out[:, :, 0:250] = initial spike section ----------------
__global__ void k_copy0(const float* __restrict__ iss, float* __restrict__ out) {
    int i = blockIdx.x * 256 + threadIdx.x;
    if (i >= B_ * R_ * NF_) return;
    int k = i % NF_;
    int br = i / NF_;
    int b = br >> 7;
    out[(size_t)br * NB_ + k] = iss[b * NF_ + k];
}

// ---------------- scan: 4 lanes per chain, DPP butterfly reduce ----------------
__global__ __launch_bounds__(256) void k_scan(const double* __restrict__ gensig,
                                              const float* __restrict__ u,
                                              const float* __restrict__ iss,
                                              const float* __restrict__ ff,
                                              float* __restrict__ out) {
    __shared__ double T[32 * 256];   // 64 KB byte-LUT: T[pos*256+m] = sum ff[8p+i] over set bits
    int tid = threadIdx.x;
    int b = blockIdx.x >> 1;
    int rbase = (blockIdx.x & 1) * 64;
    int c = tid >> 2, j = tid & 3;
    int r = rbase + c;

    // build LUT: 8 threads per pos, 32 entries each
    {
        int pos = tid >> 3;
        double f[8];
#pragma unroll
        for (int i = 0; i < 8; ++i) {
            int k = pos * 8 + i;
            f[i] = (k < NF_) ? (double)ff[k] : 0.0;
        }
        int m0 = (tid & 7) * 32;
        for (int m = m0; m < m0 + 32; ++m) {
            double s = 0.0;
#pragma unroll
            for (int i = 0; i < 8; ++i)
                if ((m >> i) & 1) s += f[i];
            T[pos * 256 + m] = s;
        }
    }

    // init replicated window: bit k = iss[b,k]
    unsigned long long w0 = 0, w1 = 0, w2 = 0, w3 = 0;
    for (int k = 0; k < NF_; ++k) {
        unsigned long long bit = (iss[b * NF_ + k] > 0.5f) ? 1ull : 0ull;
        if      (k <  64) w0 |= bit << k;
        else if (k < 128) w1 |= bit << (k - 64);
        else if (k < 192) w2 |= bit << (k - 128);
        else              w3 |= bit << (k - 192);
    }
    __syncthreads();

    const double* gs = gensig + (size_t)b * LS_;
    const float*  up = u + (size_t)b * R_ + r;
    float*        op = out + ((size_t)(b * R_ + r)) * NB_ + NF_;
    int shj = j * 8;
    const double* Tj = T + j * 256;   // + w*1024 per word

    // prologue: logit for steps j of block 0; gensig for block 0
    double mylu = lu_of(up[(size_t)j * BR_]);
    double g0 = gs[0], g1 = gs[1], g2 = gs[2], g3 = gs[3];

#define STEP(S, GC) { \
    double lu = dpp64<(S) * 0x55>(mylu); \
    unsigned x0 = (unsigned)w0, x1 = (unsigned)(w0 >> 32); \
    unsigned x2 = (unsigned)w1, x3 = (unsigned)(w1 >> 32); \
    unsigned x4 = (unsigned)w2, x5 = (unsigned)(w2 >> 32); \
    unsigned x6 = (unsigned)w3, x7 = (unsigned)(w3 >> 32); \
    double a0 = Tj[0 * 1024 + ((x0 >> shj) & 255u)]; \
    double a1 = Tj[1 * 1024 + ((x1 >> shj) & 255u)]; \
    double a2 = Tj[2 * 1024 + ((x2 >> shj) & 255u)]; \
    double a3 = Tj[3 * 1024 + ((x3 >> shj) & 255u)]; \
    double a4 = Tj[4 * 1024 + ((x4 >> shj) & 255u)]; \
    double a5 = Tj[5 * 1024 + ((x5 >> shj) & 255u)]; \
    double a6 = Tj[6 * 1024 + ((x6 >> shj) & 255u)]; \
    double a7 = Tj[7 * 1024 + ((x7 >> shj) & 255u)]; \
    double s = ((a0 + a1) + (a2 + a3)) + ((a4 + a5) + (a6 + a7)); \
    s += dpp64<0xB1>(s); \
    s += dpp64<0x4E>(s); \
    bool sp = ((GC) + s) > lu; \
    w0 = (w0 >> 1) | (w1 << 63); \
    w1 = (w1 >> 1) | (w2 << 63); \
    w2 = (w2 >> 1) | (w3 << 63); \
    w3 = (w3 >> 1) | ((unsigned long long)(sp ? 1 : 0) << 57); \
}

    for (int t0 = 0; t0 < LS_ - 2; t0 += 4) {
        // prefetch next block's u and gensig (off critical path)
        int tn = t0 + 4 + j; if (tn > LS_ - 1) tn = LS_ - 1;
        float un = up[(size_t)tn * BR_];
        int tg = t0 + 4;
        double ng0 = gs[(tg     > LS_ - 1) ? LS_ - 1 : tg];
        double ng1 = gs[(tg + 1 > LS_ - 1) ? LS_ - 1 : tg + 1];
        double ng2 = gs[(tg + 2 > LS_ - 1) ? LS_ - 1 : tg + 2];
        double ng3 = gs[(tg + 3 > LS_ - 1) ? LS_ - 1 : tg + 3];

        STEP(0, g0) STEP(1, g1) STEP(2, g2) STEP(3, g3)

        // spikes t0..t0+3 now at window bits 246..249 = w3 bits 54..57
        if (j == 0) {
            float4 o;
            o.x = (float)((w3 >> 54) & 1ull);
            o.y = (float)((w3 >> 55) & 1ull);
            o.z = (float)((w3 >> 56) & 1ull);
            o.w = (float)((w3 >> 57) & 1ull);
            *(float4*)(op + t0) = o;
        }
        g0 = ng0; g1 = ng1; g2 = ng2; g3 = ng3;
        mylu = lu_of(un);
    }
    // tail: t = 1748, 1749 (lu held in lanes j=0,1 of each group)
    STEP(0, g0) STEP(1, g1)
    if (j == 0) {
        float2 o;
        o.x = (float)((w3 >> 56) & 1ull);
        o.y = (float)((w3 >> 57) & 1ull);
        *(float2*)(op + (LS_ - 2)) = o;
    }
#undef STEP
}

extern "C" void kernel_launch(void* const* d_in, const int* in_sizes, int n_in,
                              void* d_out, int out_size, void* d_ws, size_t ws_size,
                              hipStream_t stream) {
    const float* stim_spat = (const float*)d_in[0];   // (128,2048)
    const float* stim_time = (const float*)d_in[1];   // (2000,)
    const float* iss       = (const float*)d_in[2];   // (128,250)
    const float* cc        = (const float*)d_in[3];   // (128,16,2000)
    const float* sf        = (const float*)d_in[4];   // (2048,)
    const float* bias      = (const float*)d_in[5];   // (1,)
    const float* stf       = (const float*)d_in[6];   // (250,)
    const float* ff        = (const float*)d_in[7];   // (250,)
    const float* cf        = (const float*)d_in[8];   // (16,250)
    const float* u         = (const float*)d_in[9];   // (1750,128,128)
    (void)in_sizes; (void)n_in; (void)out_size; (void)ws_size;

    float* out = (float*)d_out;                       // (128,128,2000)

    double* ws     = (double*)d_ws;
    double* gensig = ws;                              // 128*1750 f64
    double* ft     = gensig + (size_t)B_ * LS_;       // 1751 f64
    double* sdot   = ft + NT_;                        // 128 f64

    k_ft   <<<(NT_ + 255) / 256, 256, 0, stream>>>(stim_time, stf, ft);
    k_sdot <<<B_, 256, 0, stream>>>(stim_spat, sf, sdot);
    k_coup <<<dim3(7, B_), 64, 0, stream>>>(cc, cf, sdot, ft, bias, gensig);
    k_copy0<<<(B_ * R_ * NF_ + 255) / 256, 256, 0, stream>>>(iss, out);
    k_scan <<<B_ * 2, 256, 0, stream>>>(gensig, u, iss, ff, out);
}

// Round 4
// 930.126 us; speedup vs baseline: 2.3072x; 1.0447x over previous
//
#include <hip/hip_runtime.h>
#include <math.h>

#define B_  128
#define P_  2048
#define NB_ 2000
#define NF_ 250
#define NC_ 16
#define R_  128
#define LS_ 1750   // NB-NF (len_sim)
#define NT_ 1751   // NB-NF+1
#define BR_ (B_ * R_)
#define H_  16     // steps per near/far block

// ---- DPP quad-perm on f64 (2x mov_dpp b32) ----
template <int CTRL>
__device__ __forceinline__ double dpp64(double v) {
    long long x = __double_as_longlong(v);
    int lo = (int)x, hi = (int)(x >> 32);
    lo = __builtin_amdgcn_mov_dpp(lo, CTRL, 0xF, 0xF, true);
    hi = __builtin_amdgcn_mov_dpp(hi, CTRL, 0xF, 0xF, true);
    return __longlong_as_double(((long long)(unsigned)lo) | ((long long)hi << 32));
}
// xor1 = 0xB1, xor2 = 0x4E, bcast s = s*0x55

__device__ __forceinline__ double lu_of(float uf) {
    double u = (double)uf;
    return log(u / (1.0 - u));
}

// ---------------- fused: ft (blocks 0..6) + sdot (blocks 7..134) ----------------
__global__ __launch_bounds__(256) void k_pre(const float* __restrict__ st,
                                             const float* __restrict__ stf,
                                             const float* __restrict__ sp,
                                             const float* __restrict__ sf,
                                             double* __restrict__ ft,
                                             double* __restrict__ sdot) {
    if (blockIdx.x < 7) {
        int t = blockIdx.x * 256 + threadIdx.x;
        if (t >= NT_) return;
        double s = 0.0;
        for (int k = 0; k < NF_; ++k) s += (double)st[t + k] * (double)stf[k];
        ft[t] = s;
    } else {
        __shared__ double red[256];
        int b = blockIdx.x - 7;
        double s = 0.0;
        for (int p = threadIdx.x; p < P_; p += 256)
            s += (double)sp[(size_t)b * P_ + p] * (double)sf[p];
        red[threadIdx.x] = s;
        __syncthreads();
        for (int off = 128; off > 0; off >>= 1) {
            if (threadIdx.x < off) red[threadIdx.x] += red[threadIdx.x + off];
            __syncthreads();
        }
        if (threadIdx.x == 0) sdot[b] = red[0];
    }
}

// ---------------- gensig[b,t] = sdot[b]*ft[t] + bias + coup[b,t], f64 ----------------
// 256 threads = 4 waves; wave w handles channels {w, w+4, w+8, w+12}; LDS reduce.
__global__ __launch_bounds__(256) void k_coup(const float* __restrict__ cc,
                                              const float* __restrict__ cf,
                                              const double* __restrict__ sdot,
                                              const double* __restrict__ ft,
                                              const float* __restrict__ bias,
                                              double* __restrict__ gensig) {
    __shared__ __align__(16) float  ccs[NC_ * 512];   // 32 KB
    __shared__ __align__(16) double cfs[NC_ * 256];   // 32 KB
    __shared__ double red[3][64][4];                  // 6 KB
    int b = blockIdx.y, t0 = blockIdx.x * 256;
    int tid = threadIdx.x, lane = tid & 63, wv = tid >> 6;

    for (int idx = tid; idx < NC_ * 128; idx += 256) {
        int c = idx >> 7, j4 = (idx & 127) * 4, src = t0 + j4;
        const float* p = cc + ((size_t)b * NC_ + c) * NB_ + src;
        float4 v;
        if (src + 3 < NB_) v = *(const float4*)p;
        else {
            v.x = (src     < NB_) ? p[0] : 0.f;
            v.y = (src + 1 < NB_) ? p[1] : 0.f;
            v.z = (src + 2 < NB_) ? p[2] : 0.f;
            v.w = (src + 3 < NB_) ? p[3] : 0.f;
        }
        *(float4*)&ccs[c * 512 + j4] = v;
    }
    for (int idx = tid; idx < NC_ * 256; idx += 256) {
        int c = idx >> 8, k = idx & 255;
        cfs[idx] = (k < NF_) ? (double)cf[c * NF_ + k] : 0.0;
    }
    __syncthreads();

    double a0 = 0, a1 = 0, a2 = 0, a3 = 0;
    int base = lane * 4;
    for (int c = wv; c < NC_; c += 4) {
        const float*  row  = &ccs[c * 512];
        const double* crow = &cfs[c * 256];
        float4 cur = *(const float4*)&row[base];
        for (int k4 = 0; k4 < 252; k4 += 4) {
            float4 nxt = *(const float4*)&row[base + k4 + 4];
            double e0 = cur.x, e1 = cur.y, e2 = cur.z, e3 = cur.w;
            double e4 = nxt.x, e5 = nxt.y, e6 = nxt.z;
            double c0 = crow[k4], c1 = crow[k4 + 1], c2 = crow[k4 + 2], c3 = crow[k4 + 3];
            a0 += e0 * c0 + e1 * c1 + e2 * c2 + e3 * c3;
            a1 += e1 * c0 + e2 * c1 + e3 * c2 + e4 * c3;
            a2 += e2 * c0 + e3 * c1 + e4 * c2 + e5 * c3;
            a3 += e3 * c0 + e4 * c1 + e5 * c2 + e6 * c3;
            cur = nxt;
        }
    }
    if (wv > 0) {
        red[wv - 1][lane][0] = a0; red[wv - 1][lane][1] = a1;
        red[wv - 1][lane][2] = a2; red[wv - 1][lane][3] = a3;
    }
    __syncthreads();
    if (wv == 0) {
        a0 += red[0][lane][0] + red[1][lane][0] + red[2][lane][0];
        a1 += red[0][lane][1] + red[1][lane][1] + red[2][lane][1];
        a2 += red[0][lane][2] + red[1][lane][2] + red[2][lane][2];
        a3 += red[0][lane][3] + red[1][lane][3] + red[2][lane][3];
        double gb = (double)bias[0];
        double sd = sdot[b];
        double accs[4] = {a0, a1, a2, a3};
        int tb = t0 + base;
        for (int i = 0; i < 4; ++i) {
            int t = tb + i;
            if (t < LS_) gensig[(size_t)b * LS_ + t] = sd * ft[t] + gb + accs[i];
        }
    }
}

// ---------------- scan: near/far split, H=16, 4 lanes/chain ----------------
__global__ __launch_bounds__(256) void k_scan(const double* __restrict__ gensig,
                                              const float* __restrict__ u,
                                              const float* __restrict__ iss,
                                              const float* __restrict__ ff,
                                              float* __restrict__ out) {
    __shared__ double T[32 * 256];   // 64 KB byte-LUT
    int tid = threadIdx.x;
    int b = blockIdx.x >> 1;
    int rbase = (blockIdx.x & 1) * 64;
    int c = tid >> 2, j_ = tid & 3;
    int r = rbase + c;

    // ---- copy initial spike section for this block's 64 chains ----
    for (int idx = tid; idx < 64 * NF_; idx += 256) {
        int ch = idx / NF_, k = idx - ch * NF_;
        out[((size_t)(b * R_ + rbase + ch)) * NB_ + k] = iss[b * NF_ + k];
    }

    // ---- build LUT ----
    {
        int pos = tid >> 3;
        double f[8];
#pragma unroll
        for (int i = 0; i < 8; ++i) {
            int k = pos * 8 + i;
            f[i] = (k < NF_) ? (double)ff[k] : 0.0;
        }
        int m0 = (tid & 7) * 32;
        for (int m = m0; m < m0 + 32; ++m) {
            double s = 0.0;
#pragma unroll
            for (int i = 0; i < 8; ++i)
                if ((m >> i) & 1) s += f[i];
            T[pos * 256 + m] = s;
        }
    }

    // ---- init window (replicated, lockstep across 4 lanes) ----
    unsigned long long w0 = 0, w1 = 0, w2 = 0, w3 = 0;
    for (int k = 0; k < NF_; ++k) {
        unsigned long long bit = (iss[b * NF_ + k] > 0.5f) ? 1ull : 0ull;
        if      (k <  64) w0 |= bit << k;
        else if (k < 128) w1 |= bit << (k - 64);
        else if (k < 192) w2 |= bit << (k - 128);
        else              w3 |= bit << (k - 192);
    }
    __syncthreads();

    const double* gs = gensig + (size_t)b * LS_;
    const float*  up = u + (size_t)b * R_ + r;
    float*        op = out + ((size_t)(b * R_ + r)) * NB_ + NF_;
    int shj = j_ * 8;
    const double* Tj = T + j_ * 256;

    // near taps: lane j_ covers ages d = 4j_..4j_+3 -> taps ff[249-d]
    double tp0 = (double)ff[249 - 4 * j_];
    double tp1 = (double)ff[248 - 4 * j_];
    double tp2 = (double)ff[247 - 4 * j_];
    double tp3 = (double)ff[246 - 4 * j_];

    for (int t0 = 0; t0 < LS_; t0 += H_) {
        // ---- prefetch gensig + u, compute logits (off serial path) ----
        double gsv[H_];
#pragma unroll
        for (int i = 0; i < H_; ++i) {
            int tt = t0 + i; if (tt > LS_ - 1) tt = LS_ - 1;
            gsv[i] = gs[tt];
        }
        double mylu0, mylu1, mylu2, mylu3;
        {
            int t_;
            t_ = t0 +  0 + j_; if (t_ > LS_ - 1) t_ = LS_ - 1;
            float u0 = up[(size_t)t_ * BR_];
            t_ = t0 +  4 + j_; if (t_ > LS_ - 1) t_ = LS_ - 1;
            float u1 = up[(size_t)t_ * BR_];
            t_ = t0 +  8 + j_; if (t_ > LS_ - 1) t_ = LS_ - 1;
            float u2 = up[(size_t)t_ * BR_];
            t_ = t0 + 12 + j_; if (t_ > LS_ - 1) t_ = LS_ - 1;
            float u3 = up[(size_t)t_ * BR_];
            mylu0 = lu_of(u0); mylu1 = lu_of(u1); mylu2 = lu_of(u2); mylu3 = lu_of(u3);
        }

        // ---- FAR: 16 independent 32-lookup dots on frozen window ----
        double far_[H_];
        unsigned long long ws0 = w0, ws1 = w1, ws2 = w2, ws3 = w3;
#define FAR(i) { \
        unsigned x0 = (unsigned)ws0, x1 = (unsigned)(ws0 >> 32); \
        unsigned x2 = (unsigned)ws1, x3 = (unsigned)(ws1 >> 32); \
        unsigned x4 = (unsigned)ws2, x5 = (unsigned)(ws2 >> 32); \
        unsigned x6 = (unsigned)ws3, x7 = (unsigned)(ws3 >> 32); \
        double a0 = Tj[0 * 1024 + ((x0 >> shj) & 255u)]; \
        double a1 = Tj[1 * 1024 + ((x1 >> shj) & 255u)]; \
        double a2 = Tj[2 * 1024 + ((x2 >> shj) & 255u)]; \
        double a3 = Tj[3 * 1024 + ((x3 >> shj) & 255u)]; \
        double a4 = Tj[4 * 1024 + ((x4 >> shj) & 255u)]; \
        double a5 = Tj[5 * 1024 + ((x5 >> shj) & 255u)]; \
        double a6 = Tj[6 * 1024 + ((x6 >> shj) & 255u)]; \
        double a7 = Tj[7 * 1024 + ((x7 >> shj) & 255u)]; \
        double s = ((a0 + a1) + (a2 + a3)) + ((a4 + a5) + (a6 + a7)); \
        s += dpp64<0xB1>(s); \
        s += dpp64<0x4E>(s); \
        far_[i] = s + gsv[i]; \
        ws0 = (ws0 >> 1) | (ws1 << 63); \
        ws1 = (ws1 >> 1) | (ws2 << 63); \
        ws2 = (ws2 >> 1) | (ws3 << 63); \
        ws3 =  ws3 >> 1; \
}
        FAR(0)  FAR(1)  FAR(2)  FAR(3)  FAR(4)  FAR(5)  FAR(6)  FAR(7)
        FAR(8)  FAR(9)  FAR(10) FAR(11) FAR(12) FAR(13) FAR(14) FAR(15)
#undef FAR

        // ---- NEAR: 16 serial steps, registers + DPP only ----
        unsigned qreg = 0;   // bit d = spike at step (i-1-d)
#define NSTEP(i, S, MYLU) { \
        double lu = dpp64<(S) * 0x55>(MYLU); \
        unsigned qb = qreg >> (4 * j_); \
        double n0 = (qb & 1u) ? tp0 : 0.0; \
        double n1 = (qb & 2u) ? tp1 : 0.0; \
        double n2 = (qb & 4u) ? tp2 : 0.0; \
        double n3 = (qb & 8u) ? tp3 : 0.0; \
        double ns = (n0 + n1) + (n2 + n3); \
        ns += dpp64<0xB1>(ns); \
        ns += dpp64<0x4E>(ns); \
        bool sp = (far_[i] + ns) > lu; \
        qreg = (qreg << 1) | (sp ? 1u : 0u); \
}
        NSTEP(0,  0, mylu0) NSTEP(1,  1, mylu0) NSTEP(2,  2, mylu0) NSTEP(3,  3, mylu0)
        NSTEP(4,  0, mylu1) NSTEP(5,  1, mylu1) NSTEP(6,  2, mylu1) NSTEP(7,  3, mylu1)
        NSTEP(8,  0, mylu2) NSTEP(9,  1, mylu2) NSTEP(10, 2, mylu2) NSTEP(11, 3, mylu2)
        NSTEP(12, 0, mylu3) NSTEP(13, 1, mylu3) NSTEP(14, 2, mylu3) NSTEP(15, 3, mylu3)
#undef NSTEP

        // ---- write outputs + advance window ----
        unsigned q2 = __brev(qreg) >> 16;   // bit m = spike at step m
        int rem = LS_ - t0; if (rem > H_) rem = H_;
        int s0 = 4 * j_;
        if (s0 + 3 < rem) {
            float4 o;
            o.x = (float)((q2 >> (s0    )) & 1u);
            o.y = (float)((q2 >> (s0 + 1)) & 1u);
            o.z = (float)((q2 >> (s0 + 2)) & 1u);
            o.w = (float)((q2 >> (s0 + 3)) & 1u);
            *(float4*)(op + t0 + s0) = o;
        } else {
#pragma unroll
            for (int e = 0; e < 4; ++e)
                if (s0 + e < rem) op[t0 + s0 + e] = (float)((q2 >> (s0 + e)) & 1u);
        }
        w0 = (w0 >> 16) | (w1 << 48);
        w1 = (w1 >> 16) | (w2 << 48);
        w2 = (w2 >> 16) | (w3 << 48);
        w3 = (w3 >> 16) | ((unsigned long long)q2 << 42);   // bits 234..249
    }
}

extern "C" void kernel_launch(void* const* d_in, const int* in_sizes, int n_in,
                              void* d_out, int out_size, void* d_ws, size_t ws_size,
                              hipStream_t stream) {
    const float* stim_spat = (const float*)d_in[0];   // (128,2048)
    const float* stim_time = (const float*)d_in[1];   // (2000,)
    const float* iss       = (const float*)d_in[2];   // (128,250)
    const float* cc        = (const float*)d_in[3];   // (128,16,2000)
    const float* sf        = (const float*)d_in[4];   // (2048,)
    const float* bias      = (const float*)d_in[5];   // (1,)
    const float* stf       = (const float*)d_in[6];   // (250,)
    const float* ff        = (const float*)d_in[7];   // (250,)
    const float* cf        = (const float*)d_in[8];   // (16,250)
    const float* u         = (const float*)d_in[9];   // (1750,128,128)
    (void)in_sizes; (void)n_in; (void)out_size; (void)ws_size;

    float* out = (float*)d_out;                       // (128,128,2000)

    double* ws     = (double*)d_ws;
    double* gensig = ws;                              // 128*1750 f64
    double* ft     = gensig + (size_t)B_ * LS_;       // 1751 f64
    double* sdot   = ft + NT_;                        // 128 f64

    k_pre  <<<135, 256, 0, stream>>>(stim_time, stf, stim_spat, sf, ft, sdot);
    k_coup <<<dim3(7, B_), 256, 0, stream>>>(cc, cf, sdot, ft, bias, gensig);
    k_scan <<<B_ * 2, 256, 0, stream>>>(gensig, u, iss, ff, out);
}

// Round 5
// 589.273 us; speedup vs baseline: 3.6418x; 1.5784x over previous
//
#include <hip/hip_runtime.h>
#include <math.h>

#define B_  128
#define P_  2048
#define NB_ 2000
#define NF_ 250
#define NC_ 16
#define R_  128
#define LS_ 1750   // NB-NF (len_sim)
#define NT_ 1751   // NB-NF+1
#define BR_ (B_ * R_)
#define H_  16     // steps per near/far block

typedef int v4i __attribute__((ext_vector_type(4)));

// ---- DPP quad-perm on f64 (2x mov_dpp b32) ----
template <int CTRL>
__device__ __forceinline__ double dpp64(double v) {
    long long x = __double_as_longlong(v);
    int lo = (int)x, hi = (int)(x >> 32);
    lo = __builtin_amdgcn_mov_dpp(lo, CTRL, 0xF, 0xF, true);
    hi = __builtin_amdgcn_mov_dpp(hi, CTRL, 0xF, 0xF, true);
    return __longlong_as_double(((long long)(unsigned)lo) | ((long long)hi << 32));
}
// xor1 = 0xB1, xor2 = 0x4E, bcast s = s*0x55

__device__ __forceinline__ double lu_of(float uf) {
    double u = (double)uf;
    return log(u / (1.0 - u));
}

// ---------------- fused: ft (blocks 0..6) + sdot (blocks 7..134) ----------------
__global__ __launch_bounds__(256) void k_pre(const float* __restrict__ st,
                                             const float* __restrict__ stf,
                                             const float* __restrict__ sp,
                                             const float* __restrict__ sf,
                                             double* __restrict__ ft,
                                             double* __restrict__ sdot) {
    if (blockIdx.x < 7) {
        int t = blockIdx.x * 256 + threadIdx.x;
        if (t >= NT_) return;
        double s = 0.0;
        for (int k = 0; k < NF_; ++k) s += (double)st[t + k] * (double)stf[k];
        ft[t] = s;
    } else {
        __shared__ double red[256];
        int b = blockIdx.x - 7;
        double s = 0.0;
        for (int p = threadIdx.x; p < P_; p += 256)
            s += (double)sp[(size_t)b * P_ + p] * (double)sf[p];
        red[threadIdx.x] = s;
        __syncthreads();
        for (int off = 128; off > 0; off >>= 1) {
            if (threadIdx.x < off) red[threadIdx.x] += red[threadIdx.x + off];
            __syncthreads();
        }
        if (threadIdx.x == 0) sdot[b] = red[0];
    }
}

// ---------------- gensig[b,t] = sdot[b]*ft[t] + bias + coup[b,t], f64 ----------------
__global__ __launch_bounds__(256) void k_coup(const float* __restrict__ cc,
                                              const float* __restrict__ cf,
                                              const double* __restrict__ sdot,
                                              const double* __restrict__ ft,
                                              const float* __restrict__ bias,
                                              double* __restrict__ gensig) {
    __shared__ __align__(16) float  ccs[NC_ * 512];   // 32 KB
    __shared__ __align__(16) double cfs[NC_ * 256];   // 32 KB
    __shared__ double red[3][64][4];                  // 6 KB
    int b = blockIdx.y, t0 = blockIdx.x * 256;
    int tid = threadIdx.x, lane = tid & 63, wv = tid >> 6;

    for (int idx = tid; idx < NC_ * 128; idx += 256) {
        int c = idx >> 7, j4 = (idx & 127) * 4, src = t0 + j4;
        const float* p = cc + ((size_t)b * NC_ + c) * NB_ + src;
        float4 v;
        if (src + 3 < NB_) v = *(const float4*)p;
        else {
            v.x = (src     < NB_) ? p[0] : 0.f;
            v.y = (src + 1 < NB_) ? p[1] : 0.f;
            v.z = (src + 2 < NB_) ? p[2] : 0.f;
            v.w = (src + 3 < NB_) ? p[3] : 0.f;
        }
        *(float4*)&ccs[c * 512 + j4] = v;
    }
    for (int idx = tid; idx < NC_ * 256; idx += 256) {
        int c = idx >> 8, k = idx & 255;
        cfs[idx] = (k < NF_) ? (double)cf[c * NF_ + k] : 0.0;
    }
    __syncthreads();

    double a0 = 0, a1 = 0, a2 = 0, a3 = 0;
    int base = lane * 4;
    for (int c = wv; c < NC_; c += 4) {
        const float*  row  = &ccs[c * 512];
        const double* crow = &cfs[c * 256];
        float4 cur = *(const float4*)&row[base];
        for (int k4 = 0; k4 < 252; k4 += 4) {
            float4 nxt = *(const float4*)&row[base + k4 + 4];
            double e0 = cur.x, e1 = cur.y, e2 = cur.z, e3 = cur.w;
            double e4 = nxt.x, e5 = nxt.y, e6 = nxt.z;
            double c0 = crow[k4], c1 = crow[k4 + 1], c2 = crow[k4 + 2], c3 = crow[k4 + 3];
            a0 += e0 * c0 + e1 * c1 + e2 * c2 + e3 * c3;
            a1 += e1 * c0 + e2 * c1 + e3 * c2 + e4 * c3;
            a2 += e2 * c0 + e3 * c1 + e4 * c2 + e5 * c3;
            a3 += e3 * c0 + e4 * c1 + e5 * c2 + e6 * c3;
            cur = nxt;
        }
    }
    if (wv > 0) {
        red[wv - 1][lane][0] = a0; red[wv - 1][lane][1] = a1;
        red[wv - 1][lane][2] = a2; red[wv - 1][lane][3] = a3;
    }
    __syncthreads();
    if (wv == 0) {
        a0 += red[0][lane][0] + red[1][lane][0] + red[2][lane][0];
        a1 += red[0][lane][1] + red[1][lane][1] + red[2][lane][1];
        a2 += red[0][lane][2] + red[1][lane][2] + red[2][lane][2];
        a3 += red[0][lane][3] + red[1][lane][3] + red[2][lane][3];
        double gb = (double)bias[0];
        double sd = sdot[b];
        double accs[4] = {a0, a1, a2, a3};
        int tb = t0 + base;
        for (int i = 0; i < 4; ++i) {
            int t = tb + i;
            if (t < LS_) gensig[(size_t)b * LS_ + t] = sd * ft[t] + gb + accs[i];
        }
    }
}

// ---------------- scan: i8-MFMA far + quad-DPP near. One wave = 16 chains. ----------------
// wave gw: b = gw>>3, rbase = (gw&7)*16. Lane roles:
//   lw = lane&15 : window-chain (MFMA A row), MFMA B col / C col (step)
//   q  = lane>>4 : MFMA K-quad
//   cn = lane>>2 : near chain; j = lane&3 : near sub-lane (ages 4j+1..4j+4)
__global__ __launch_bounds__(256, 1) void k_scan(const double* __restrict__ gensig,
                                                 const float* __restrict__ u,
                                                 const float* __restrict__ iss,
                                                 const float* __restrict__ ff,
                                                 float* __restrict__ out) {
    __shared__ double   farT_all[4][16 * 17];
    __shared__ unsigned q2_all[4][16];
    int tid = threadIdx.x;
    int wv = tid >> 6, l = tid & 63;
    int gw = blockIdx.x * 4 + wv;
    int b = gw >> 3, rbase = (gw & 7) * 16;
    double*   farT = &farT_all[wv][0];
    unsigned* q2s  = &q2_all[wv][0];

    int lw = l & 15;
    int q  = l >> 4;
    int cn = l >> 2;
    int j  = l & 3;

    // ---- iss -> out[.., 0:250] for this wave's 16 chains ----
    const float* issb = iss + b * NF_;
    for (int idx = l; idx < 16 * NF_; idx += 64) {
        int c = idx / NF_, k = idx - c * NF_;
        out[((size_t)(b * R_ + rbase + c)) * NB_ + k] = issb[k];
    }

    // ---- window init: PW[k] = spike(t0-250+k), k=0..249; bits 250..255 = 0 ----
    unsigned long long W[4] = {0ull, 0ull, 0ull, 0ull};
    for (int k = 0; k < NF_; ++k) {
        unsigned long long bit = (issb[k] > 0.5f) ? 1ull : 0ull;
        W[k >> 6] |= bit << (k & 63);
    }

    // ---- B digit planes: Bf[chunk][plane]; F[k][n] = digit_p(rint(ff[k-n]*2^48)) ----
    int Bword[4][7][4];
#pragma unroll
    for (int kc = 0; kc < 4; ++kc)
#pragma unroll
        for (int p = 0; p < 7; ++p)
#pragma unroll
            for (int w = 0; w < 4; ++w) Bword[kc][p][w] = 0;
#pragma unroll
    for (int kc = 0; kc < 4; ++kc) {
#pragma unroll
        for (int jj = 0; jj < 16; ++jj) {
            int k = kc * 64 + q * 16 + jj;
            int idx = k - lw;
            long long v = 0;
            if (idx >= 0 && idx < NF_)
                v = __double2ll_rn((double)ff[idx] * 281474976710656.0); // * 2^48
#pragma unroll
            for (int p = 0; p < 7; ++p) {
                int d = (int)((v + 128) & 255) - 128;
                v = (v - (long long)d) >> 8;
                Bword[kc][p][jj >> 2] |= (d & 255) << ((jj & 3) * 8);
            }
        }
    }
    v4i Bf[4][7];
#pragma unroll
    for (int kc = 0; kc < 4; ++kc)
#pragma unroll
        for (int p = 0; p < 7; ++p) {
            v4i t; t.x = Bword[kc][p][0]; t.y = Bword[kc][p][1];
            t.z = Bword[kc][p][2]; t.w = Bword[kc][p][3];
            Bf[kc][p] = t;
        }

    const double* gs = gensig + (size_t)b * LS_;
    const float*  up = u + b * R_ + rbase + cn;
    float*        op = out + ((size_t)(b * R_ + rbase + cn)) * NB_ + NF_;

    // near taps: lane j covers ages 4j+1..4j+4 -> ff[249-4j..246-4j]
    double tp0 = (double)ff[249 - 4 * j];
    double tp1 = (double)ff[248 - 4 * j];
    double tp2 = (double)ff[247 - 4 * j];
    double tp3 = (double)ff[246 - 4 * j];

    // pipeline state
    double farv[16];
    double mylu0 = 0, mylu1 = 0, mylu2 = 0, mylu3 = 0;
    float  uraw0, uraw1, uraw2, uraw3;
    double gprep = gs[lw];                 // gensig col for block P=0
    {
        int t_;
        t_ = 0  + j; if (t_ > LS_ - 1) t_ = LS_ - 1; uraw0 = up[(size_t)t_ * BR_];
        t_ = 4  + j; if (t_ > LS_ - 1) t_ = LS_ - 1; uraw1 = up[(size_t)t_ * BR_];
        t_ = 8  + j; if (t_ > LS_ - 1) t_ = LS_ - 1; uraw2 = up[(size_t)t_ * BR_];
        t_ = 12 + j; if (t_ > LS_ - 1) t_ = LS_ - 1; uraw3 = up[(size_t)t_ * BR_];
    }

#define NSTEP(i, S, MYLU) { \
    double lu = dpp64<(S) * 0x55>(MYLU); \
    unsigned qb = qreg >> (4 * j); \
    double n0 = (qb & 1u) ? tp0 : 0.0; \
    double n1 = (qb & 2u) ? tp1 : 0.0; \
    double n2 = (qb & 4u) ? tp2 : 0.0; \
    double n3 = (qb & 8u) ? tp3 : 0.0; \
    double ns = (n0 + n1) + (n2 + n3); \
    ns += dpp64<0xB1>(ns); \
    ns += dpp64<0x4E>(ns); \
    bool sp = (farv[i] + ns) > lu; \
    qreg = (qreg << 1) | (sp ? 1u : 0u); \
}

    for (int t0 = -H_; t0 < LS_; t0 += H_) {
        if (t0 >= 0) {
            // ---- NEAR: 16 serial steps (registers + DPP only) ----
            unsigned qreg = 0;
            NSTEP(0,  0, mylu0) NSTEP(1,  1, mylu0) NSTEP(2,  2, mylu0) NSTEP(3,  3, mylu0)
            NSTEP(4,  0, mylu1) NSTEP(5,  1, mylu1) NSTEP(6,  2, mylu1) NSTEP(7,  3, mylu1)
            NSTEP(8,  0, mylu2) NSTEP(9,  1, mylu2) NSTEP(10, 2, mylu2) NSTEP(11, 3, mylu2)
            NSTEP(12, 0, mylu3) NSTEP(13, 1, mylu3) NSTEP(14, 2, mylu3) NSTEP(15, 3, mylu3)

            unsigned q2 = __brev(qreg) >> 16;   // bit i = spike at step t0+i
            int rem = LS_ - t0; if (rem > H_) rem = H_;
            int s0 = 4 * j;
            if (s0 + 3 < rem) {
                float4 o;
                o.x = (float)((q2 >> (s0    )) & 1u);
                o.y = (float)((q2 >> (s0 + 1)) & 1u);
                o.z = (float)((q2 >> (s0 + 2)) & 1u);
                o.w = (float)((q2 >> (s0 + 3)) & 1u);
                *(float4*)(op + t0 + s0) = o;
            } else {
#pragma unroll
                for (int e = 0; e < 4; ++e)
                    if (s0 + e < rem) op[t0 + s0 + e] = (float)((q2 >> (s0 + e)) & 1u);
            }
            // broadcast q2 (chain cn) -> window owners (chain lw)
            if (j == 0) q2s[cn] = q2;
            __asm__ volatile("s_waitcnt lgkmcnt(0)" ::: "memory");
            unsigned long long q2n = (unsigned long long)q2s[lw];
            W[0] = (W[0] >> 16) | (W[1] << 48);
            W[1] = (W[1] >> 16) | (W[2] << 48);
            W[2] = (W[2] >> 16) | (W[3] << 48);
            W[3] = (W[3] >> 16) | (q2n << 42);   // new spikes at k=234..249
        }

        int P = t0 + H_;
        if (P < LS_) {
            // ---- FAR via i8 MFMA: fb_far[m,n] = sum_k PW[m][k] * F[k][n] ----
            v4i acc[7];
#pragma unroll
            for (int p = 0; p < 7; ++p) acc[p] = (v4i){0, 0, 0, 0};
#pragma unroll
            for (int kc = 0; kc < 4; ++kc) {
                unsigned field = (unsigned)((W[kc] >> (q * 16)) & 0xFFFFull);
                v4i av;
                av.x = (int)((((field      ) & 0xFu) * 0x00204081u) & 0x01010101u);
                av.y = (int)((((field >>  4) & 0xFu) * 0x00204081u) & 0x01010101u);
                av.z = (int)((((field >>  8) & 0xFu) * 0x00204081u) & 0x01010101u);
                av.w = (int)((((field >> 12) & 0xFu) * 0x00204081u) & 0x01010101u);
#pragma unroll
                for (int p = 0; p < 7; ++p)
                    acc[p] = __builtin_amdgcn_mfma_i32_16x16x64_i8(av, Bf[kc][p], acc[p], 0, 0, 0);
            }
            // ---- combine planes (exact in f64), add gensig, transpose via LDS ----
#pragma unroll
            for (int r = 0; r < 4; ++r) {
                double fb = gprep;
#pragma unroll
                for (int p = 0; p < 7; ++p)
                    fb += (double)acc[p][r] * ldexp(1.0, 8 * p - 48);
                farT[(q * 4 + r) * 17 + lw] = fb;
            }
            __asm__ volatile("s_waitcnt lgkmcnt(0)" ::: "memory");
#pragma unroll
            for (int i = 0; i < 16; ++i) farv[i] = farT[cn * 17 + i];

            // gensig col for block P+H (clamped)
            {
                int tg = P + H_ + lw; if (tg > LS_ - 1) tg = LS_ - 1;
                gprep = gs[tg];
            }
            // logits for block P (u loaded last iteration)
            mylu0 = lu_of(uraw0); mylu1 = lu_of(uraw1);
            mylu2 = lu_of(uraw2); mylu3 = lu_of(uraw3);
            // u for block P+H (clamped)
            {
                int t_;
                t_ = P + H_ +  0 + j; if (t_ > LS_ - 1) t_ = LS_ - 1; uraw0 = up[(size_t)t_ * BR_];
                t_ = P + H_ +  4 + j; if (t_ > LS_ - 1) t_ = LS_ - 1; uraw1 = up[(size_t)t_ * BR_];
                t_ = P + H_ +  8 + j; if (t_ > LS_ - 1) t_ = LS_ - 1; uraw2 = up[(size_t)t_ * BR_];
                t_ = P + H_ + 12 + j; if (t_ > LS_ - 1) t_ = LS_ - 1; uraw3 = up[(size_t)t_ * BR_];
            }
        }
    }
#undef NSTEP
}

extern "C" void kernel_launch(void* const* d_in, const int* in_sizes, int n_in,
                              void* d_out, int out_size, void* d_ws, size_t ws_size,
                              hipStream_t stream) {
    const float* stim_spat = (const float*)d_in[0];   // (128,2048)
    const float* stim_time = (const float*)d_in[1];   // (2000,)
    const float* iss       = (const float*)d_in[2];   // (128,250)
    const float* cc        = (const float*)d_in[3];   // (128,16,2000)
    const float* sf        = (const float*)d_in[4];   // (2048,)
    const float* bias      = (const float*)d_in[5];   // (1,)
    const float* stf       = (const float*)d_in[6];   // (250,)
    const float* ff        = (const float*)d_in[7];   // (250,)
    const float* cf        = (const float*)d_in[8];   // (16,250)
    const float* u         = (const float*)d_in[9];   // (1750,128,128)
    (void)in_sizes; (void)n_in; (void)out_size; (void)ws_size;

    float* out = (float*)d_out;                       // (128,128,2000)

    double* ws     = (double*)d_ws;
    double* gensig = ws;                              // 128*1750 f64
    double* ft     = gensig + (size_t)B_ * LS_;       // 1751 f64
    double* sdot   = ft + NT_;                        // 128 f64

    k_pre  <<<135, 256, 0, stream>>>(stim_time, stf, stim_spat, sf, ft, sdot);
    k_coup <<<dim3(7, B_), 256, 0, stream>>>(cc, cf, sdot, ft, bias, gensig);
    k_scan <<<B_ * 2, 256, 0, stream>>>(gensig, u, iss, ff, out);
}